// Round 4
// baseline (266.519 us; speedup 1.0000x reference)
//
#include <hip/hip_runtime.h>
#include <hip/hip_bf16.h>
#include <math.h>

#define B_ 8
#define S_ 2048
#define D_ 1024
#define H_ 64
#define M_ (B_*S_)
#define SPLIT 4
#define KEYS_PER_SPLIT (S_/SPLIT)   // 512

typedef __attribute__((ext_vector_type(8))) short bf16x8;
typedef __attribute__((ext_vector_type(8))) unsigned short u16x8;
typedef __attribute__((ext_vector_type(4))) float f32x4;

__device__ inline unsigned short f2bf(float f) {
    unsigned int u = __builtin_bit_cast(unsigned int, f);
    u += 0x7fffu + ((u >> 16) & 1u);   // round-to-nearest-even
    return (unsigned short)(u >> 16);
}

// mask -> multiplicative 1.0/0.0. Layout sniff: jax bool may be 1-byte or int32.
__global__ __launch_bounds__(256) void mask_kernel(const unsigned char* __restrict__ mask,
                                                   float* __restrict__ mmul, int n) {
    int j = blockIdx.x * 256 + threadIdx.x;
    if (j >= n) return;
    bool boolLayout = mask[1] != 0;
    int mv = boolLayout ? (int)mask[j] : ((const int*)mask)[j];
    mmul[j] = mv ? 1.0f : 0.0f;
}

// Transpose W[1024][64] fp32 -> Wt[64][1024] bf16, one matrix per blockIdx.y.
__global__ __launch_bounds__(256) void wprep_kernel(
    const float* __restrict__ Wq, const float* __restrict__ Wk, const float* __restrict__ Wv,
    unsigned short* __restrict__ Wt)
{
    const int m = blockIdx.y;
    const float* W = (m == 0) ? Wq : (m == 1) ? Wk : Wv;
    unsigned short* Wo = Wt + (size_t)m * 64 * 1024;
    __shared__ unsigned short T[64][65];
    const int t = threadIdx.x;
    const int k0 = blockIdx.x * 64;
    #pragma unroll
    for (int i = 0; i < 16; i++) {
        int vi = t + i * 256;
        int kk = vi >> 6, n = vi & 63;
        T[kk][n] = f2bf(W[(size_t)(k0 + kk) * 64 + n]);
    }
    __syncthreads();
    #pragma unroll
    for (int i = 0; i < 4; i++) {
        int vi = t + i * 256;
        int n = vi >> 4, k4 = vi & 15;
        ushort4 u;
        u.x = T[k4*4+0][n]; u.y = T[k4*4+1][n]; u.z = T[k4*4+2][n]; u.w = T[k4*4+3][n];
        *(ushort4*)&Wo[(size_t)n * 1024 + k0 + k4*4] = u;
    }
}

// x[M,1024] @ W[1024,64] -> bf16 [M,64].  Barrier-free. Batched-load super-
// iterations (K=128): issue ALL 24 loads, sched_barrier(0) fence, then compute.
// The fence prevents the scheduler from interleaving uses between loads (the
// round-2/3 failure mode), keeping ~24 loads in flight per wave.
__global__ __launch_bounds__(256) void proj_kernel(
    const float* __restrict__ q, const float* __restrict__ kx, const float* __restrict__ vx,
    const unsigned short* __restrict__ Wt,
    unsigned short* __restrict__ qp, unsigned short* __restrict__ kp, unsigned short* __restrict__ vp)
{
    const int m = blockIdx.y;
    const float* x = (m == 0) ? q : (m == 1) ? kx : vx;
    const unsigned short* Wm = Wt + (size_t)m * 64 * 1024;
    unsigned short* outp = (m == 0) ? qp : (m == 1) ? kp : vp;

    const int t = threadIdx.x;
    const int w = t >> 6, l = t & 63;
    const int lrow = l & 15, quad = l >> 4;
    const size_t arow = (size_t)(blockIdx.x * 64 + w * 16 + lrow);
    const float* xr = x + arow * D_ + quad * 8;
    const unsigned short* wb = Wm + lrow * 1024 + quad * 8;

    f32x4 acc[4] = {};
    #pragma unroll 1
    for (int ks = 0; ks < D_; ks += 128) {          // 8 super-iterations
        float4 xa[8];
        bf16x8 wf[4][4];
        #pragma unroll
        for (int kk = 0; kk < 4; kk++) {
            xa[2*kk]   = *(const float4*)(xr + ks + kk*32);
            xa[2*kk+1] = *(const float4*)(xr + ks + kk*32 + 4);
        }
        #pragma unroll
        for (int kk = 0; kk < 4; kk++)
            #pragma unroll
            for (int c = 0; c < 4; c++)
                wf[kk][c] = *(const bf16x8*)(wb + ks + kk*32 + c * 16 * 1024);
        __builtin_amdgcn_sched_barrier(0);          // nothing crosses: loads stay batched
        #pragma unroll
        for (int kk = 0; kk < 4; kk++) {
            bf16x8 af;
            af[0] = (short)f2bf(xa[2*kk].x); af[1] = (short)f2bf(xa[2*kk].y);
            af[2] = (short)f2bf(xa[2*kk].z); af[3] = (short)f2bf(xa[2*kk].w);
            af[4] = (short)f2bf(xa[2*kk+1].x); af[5] = (short)f2bf(xa[2*kk+1].y);
            af[6] = (short)f2bf(xa[2*kk+1].z); af[7] = (short)f2bf(xa[2*kk+1].w);
            #pragma unroll
            for (int c = 0; c < 4; c++)
                acc[c] = __builtin_amdgcn_mfma_f32_16x16x32_bf16(af, wf[kk][c], acc[c], 0, 0, 0);
        }
    }
    const float sc = (m == 0) ? 0.125f : 1.0f;   // fold attention scale into qp
    const int orow = blockIdx.x * 64 + w * 16 + quad * 4;
    #pragma unroll
    for (int c = 0; c < 4; c++)
        #pragma unroll
        for (int r = 0; r < 4; r++)
            outp[(size_t)(orow + r) * H_ + c * 16 + lrow] = f2bf(acc[c][r] * sc);
}

// Flash attention partial: block = (q-tile 64, batch, key-split). Max-free
// single-pass exp => partials over disjoint key ranges combine by addition.
__global__ __launch_bounds__(256) void attn_kernel(
    const unsigned short* __restrict__ qp, const unsigned short* __restrict__ kp,
    const unsigned short* __restrict__ vp, const float* __restrict__ mmul,
    float* __restrict__ po, float* __restrict__ pl)
{
    __shared__ unsigned short Qs[64][72];
    __shared__ unsigned short Ks[64][72];
    __shared__ unsigned short Vt[64][72];   // [h][krow ^ swizzle]
    __shared__ unsigned short Ps[64][72];

    const int t = threadIdx.x;
    const int w = t >> 6, l = t & 63;
    const int lrow = l & 15, lq = l >> 4;
    const int lk8 = lq * 8;
    const int b = blockIdx.y, q0 = blockIdx.x * 64;
    const int split = blockIdx.z;
    const int key0 = split * KEYS_PER_SPLIT;
    const size_t basebs = (size_t)b * S_;

    const int srow = t >> 3, sc8 = t & 7;

    #pragma unroll
    for (int i = 0; i < 2; i++) {
        u16x8 u = *(const u16x8*)&qp[(basebs + q0 + srow + i*32) * H_ + sc8 * 8];
        *(u16x8*)&Qs[srow + i*32][sc8 * 8] = u;
    }

    u16x8 kr[2], vr[2];
    #pragma unroll
    for (int i = 0; i < 2; i++) {
        kr[i] = *(const u16x8*)&kp[(basebs + key0 + srow + i*32) * H_ + sc8 * 8];
        vr[i] = *(const u16x8*)&vp[(basebs + key0 + srow + i*32) * H_ + sc8 * 8];
    }

    float lsum[4] = {0.f, 0.f, 0.f, 0.f};
    f32x4 o[4] = {};

    for (int kt = 0; kt < KEYS_PER_SPLIT / 64; kt++) {
        __syncthreads();
        #pragma unroll
        for (int i = 0; i < 2; i++) {
            *(u16x8*)&Ks[srow + i*32][sc8 * 8] = kr[i];
            #pragma unroll
            for (int j = 0; j < 8; j++)
                Vt[sc8*8 + j][(srow + i*32) ^ (sc8*8)] = vr[i][j];
        }
        __syncthreads();
        if (kt + 1 < KEYS_PER_SPLIT / 64) {
            const int k0n = key0 + (kt + 1) * 64;
            #pragma unroll
            for (int i = 0; i < 2; i++) {
                kr[i] = *(const u16x8*)&kp[(basebs + k0n + srow + i*32) * H_ + sc8 * 8];
                vr[i] = *(const u16x8*)&vp[(basebs + k0n + srow + i*32) * H_ + sc8 * 8];
            }
        }
        const int k0 = key0 + kt * 64;
        float mm[4];
        #pragma unroll
        for (int c = 0; c < 4; c++) mm[c] = mmul[basebs + k0 + c*16 + lrow];

        f32x4 s[4] = {};
        #pragma unroll
        for (int kk = 0; kk < 2; kk++) {
            bf16x8 aq = *(const bf16x8*)&Qs[w*16 + lrow][kk*32 + lk8];
            #pragma unroll
            for (int c = 0; c < 4; c++) {
                bf16x8 bk = *(const bf16x8*)&Ks[c*16 + lrow][kk*32 + lk8];
                s[c] = __builtin_amdgcn_mfma_f32_16x16x32_bf16(aq, bk, s[c], 0, 0, 0);
            }
        }
        #pragma unroll
        for (int r = 0; r < 4; r++) {
            float p0 = __expf(s[0][r]) * mm[0];
            float p1 = __expf(s[1][r]) * mm[1];
            float p2 = __expf(s[2][r]) * mm[2];
            float p3 = __expf(s[3][r]) * mm[3];
            lsum[r] += (p0 + p1) + (p2 + p3);
            const int pr = w*16 + lq*4 + r;
            Ps[pr][ 0 + lrow] = f2bf(p0);
            Ps[pr][16 + lrow] = f2bf(p1);
            Ps[pr][32 + lrow] = f2bf(p2);
            Ps[pr][48 + lrow] = f2bf(p3);
        }
        #pragma unroll
        for (int kk = 0; kk < 2; kk++) {
            bf16x8 ap = *(const bf16x8*)&Ps[w*16 + lrow][kk*32 + lk8];
            #pragma unroll
            for (int c = 0; c < 4; c++) {
                const int h = c*16 + lrow;
                const int sw = ((h >> 3) & 7) * 8;
                bf16x8 bv = *(const bf16x8*)&Vt[h][(kk*32 + lk8) ^ sw];
                o[c] = __builtin_amdgcn_mfma_f32_16x16x32_bf16(ap, bv, o[c], 0, 0, 0);
            }
        }
    }

    float* pob = po + (size_t)split * M_ * H_;
    float* plb = pl + (size_t)split * M_;
    #pragma unroll
    for (int r = 0; r < 4; r++) {
        #pragma unroll
        for (int d = 1; d < 16; d <<= 1)
            lsum[r] += __shfl_xor(lsum[r], d, 64);
        const size_t row = basebs + q0 + w*16 + lq*4 + r;
        if (lrow == 0) plb[row] = lsum[r];
        #pragma unroll
        for (int c = 0; c < 4; c++)
            pob[row * H_ + c*16 + lrow] = o[c][r];
    }
}

// out = (sum_s po[s]) / (sum_s pl[s]); one float4 per thread.
__global__ __launch_bounds__(256) void combine_kernel(
    const float* __restrict__ po, const float* __restrict__ pl, float* __restrict__ out)
{
    const int idx = blockIdx.x * 256 + threadIdx.x;   // over M_*16 float4 chunks
    const size_t row = idx >> 4;
    const int c4 = (idx & 15) * 4;
    float lt = 0.f;
    #pragma unroll
    for (int s = 0; s < SPLIT; s++) lt += pl[(size_t)s * M_ + row];
    f32x4 acc = {};
    #pragma unroll
    for (int s = 0; s < SPLIT; s++) {
        const f32x4 p = *(const f32x4*)&po[((size_t)s * M_ + row) * H_ + c4];
        acc += p;
    }
    const float inv = 1.0f / lt;
    f32x4 r = acc * inv;
    *(f32x4*)&out[row * H_ + c4] = r;
}

extern "C" void kernel_launch(void* const* d_in, const int* in_sizes, int n_in,
                              void* d_out, int out_size, void* d_ws, size_t ws_size,
                              hipStream_t stream) {
    const float* q  = (const float*)d_in[0];
    const float* k  = (const float*)d_in[1];
    const float* v  = (const float*)d_in[2];
    const unsigned char* mask = (const unsigned char*)d_in[3];
    const float* Wq = (const float*)d_in[4];
    const float* Wk = (const float*)d_in[5];
    const float* Wv = (const float*)d_in[6];
    float* out = (float*)d_out;

    unsigned short* qp = (unsigned short*)d_ws;          // 2 MB
    unsigned short* kp = qp + (size_t)M_ * H_;           // 2 MB
    unsigned short* vp = kp + (size_t)M_ * H_;           // 2 MB
    float* mmul = (float*)(vp + (size_t)M_ * H_);        // 64 KB
    unsigned short* Wt = (unsigned short*)(mmul + M_);   // 384 KB
    float* po = (float*)(Wt + (size_t)3 * 64 * 1024);    // SPLIT*M*64 fp32 = 16.8 MB
    float* pl = po + (size_t)SPLIT * M_ * H_;            // SPLIT*M fp32 = 256 KB

    wprep_kernel<<<dim3(16, 3), dim3(256), 0, stream>>>(Wq, Wk, Wv, Wt);
    mask_kernel<<<dim3((M_ + 255)/256), dim3(256), 0, stream>>>(mask, mmul, M_);
    proj_kernel<<<dim3(M_/64, 3), dim3(256), 0, stream>>>(q, k, v, Wt, qp, kp, vp);
    attn_kernel<<<dim3(S_/64, B_, SPLIT), dim3(256), 0, stream>>>(qp, kp, vp, mmul, po, pl);
    combine_kernel<<<dim3(M_*16/256), dim3(256), 0, stream>>>(po, pl, out);
}

// Round 5
// 244.279 us; speedup vs baseline: 1.0910x; 1.0910x over previous
//
#include <hip/hip_runtime.h>
#include <hip/hip_bf16.h>
#include <math.h>

#define B_ 8
#define S_ 2048
#define D_ 1024
#define H_ 64
#define M_ (B_*S_)
#define SPLIT 4
#define KPS (S_/SPLIT)   // 512 keys per split

typedef __attribute__((ext_vector_type(8))) short bf16x8;
typedef __attribute__((ext_vector_type(8))) unsigned short u16x8;
typedef __attribute__((ext_vector_type(4))) float f32x4;

__device__ inline unsigned short f2bf(float f) {
    unsigned int u = __builtin_bit_cast(unsigned int, f);
    u += 0x7fffu + ((u >> 16) & 1u);   // round-to-nearest-even
    return (unsigned short)(u >> 16);
}

// async global->LDS, 16B per lane. LDS dst is wave-uniform base + lane*16;
// we pass base + lane*16 per lane (lane 0 supplies the base), global side is
// a true per-lane gather, which carries our bank swizzle.
__device__ inline void async16(const void* g, void* l) {
    __builtin_amdgcn_global_load_lds((const __attribute__((address_space(1))) void*)g,
                                     (__attribute__((address_space(3))) void*)l, 16, 0, 0);
}

// mask -> multiplicative 1.0/0.0. Layout sniff: jax bool may be 1-byte or int32.
__global__ __launch_bounds__(256) void mask_kernel(const unsigned char* __restrict__ mask,
                                                   float* __restrict__ mmul, int n) {
    int j = blockIdx.x * 256 + threadIdx.x;
    if (j >= n) return;
    bool boolLayout = mask[1] != 0;
    int mv = boolLayout ? (int)mask[j] : ((const int*)mask)[j];
    mmul[j] = mv ? 1.0f : 0.0f;
}

// Transpose W[1024][64] fp32 -> Wt[64][1024] bf16, one matrix per blockIdx.y.
__global__ __launch_bounds__(256) void wprep_kernel(
    const float* __restrict__ Wq, const float* __restrict__ Wk, const float* __restrict__ Wv,
    unsigned short* __restrict__ Wt)
{
    const int m = blockIdx.y;
    const float* W = (m == 0) ? Wq : (m == 1) ? Wk : Wv;
    unsigned short* Wo = Wt + (size_t)m * 64 * 1024;
    __shared__ unsigned short T[64][65];
    const int t = threadIdx.x;
    const int k0 = blockIdx.x * 64;
    #pragma unroll
    for (int i = 0; i < 16; i++) {
        int vi = t + i * 256;
        int kk = vi >> 6, n = vi & 63;
        T[kk][n] = f2bf(W[(size_t)(k0 + kk) * 64 + n]);
    }
    __syncthreads();
    #pragma unroll
    for (int i = 0; i < 4; i++) {
        int vi = t + i * 256;
        int n = vi >> 4, k4 = vi & 15;
        ushort4 u;
        u.x = T[k4*4+0][n]; u.y = T[k4*4+1][n]; u.z = T[k4*4+2][n]; u.w = T[k4*4+3][n];
        *(ushort4*)&Wo[(size_t)n * 1024 + k0 + k4*4] = u;
    }
}

// x[M,1024] @ W[1024,64].  A and W tiles staged via global_load_lds (async,
// no VGPR chain => compiler cannot serialize). XOR bank swizzle rides on the
// global-side address. m==2 (v) writes TRANSPOSED vpT[b][h][s] for attn.
__global__ __launch_bounds__(256) void proj_kernel(
    const float* __restrict__ q, const float* __restrict__ kx, const float* __restrict__ vx,
    const unsigned short* __restrict__ Wt,
    unsigned short* __restrict__ qp, unsigned short* __restrict__ kp, unsigned short* __restrict__ vpT)
{
    __shared__ float          Ax[64 * 128];   // 32 KB, chunk-swizzled
    __shared__ unsigned short Wl[64 * 128];   // 16 KB, chunk-swizzled

    const int m = blockIdx.y;
    const float* x = (m == 0) ? q : (m == 1) ? kx : vx;
    const unsigned short* Wm = Wt + (size_t)m * 64 * 1024;

    const int t = threadIdx.x;
    const int w = t >> 6, l = t & 63;
    const int lrow = l & 15, quad = l >> 4;
    const int row0 = blockIdx.x * 64;

    f32x4 acc[4] = {};

    for (int ks = 0; ks < D_; ks += 128) {
        __syncthreads();                       // prev chunk's LDS reads done
        // A tile: 64 rows x 128 fp32 = 2048 16B-chunks; phys chunk p holds
        // data (r = p>>5, col-chunk = (p&31) ^ (r&7))
        #pragma unroll
        for (int j = 0; j < 8; j++) {
            int p = (w * 8 + j) * 64 + l;
            int r = p >> 5;
            int cc = (p & 31) ^ (r & 7);
            async16(&x[(size_t)(row0 + r) * D_ + ks + cc * 4], &Ax[p * 4]);
        }
        // W tile: 64 n x 128 k bf16 = 1024 chunks; p holds (n=p>>4, kc=(p&15)^(n&7))
        #pragma unroll
        for (int j = 0; j < 4; j++) {
            int p = (w * 4 + j) * 64 + l;
            int n = p >> 4;
            int kc = (p & 15) ^ (n & 7);
            async16(&Wm[(size_t)n * 1024 + ks + kc * 8], &Wl[p * 8]);
        }
        __syncthreads();                       // drain async queue

        const int r = w * 16 + lrow;
        #pragma unroll
        for (int kk = 0; kk < 4; kk++) {
            const int c32 = kk * 8 + quad * 2;
            f32x4 a0 = *(const f32x4*)&Ax[(r * 32 + ((c32    ) ^ (r & 7))) * 4];
            f32x4 a1 = *(const f32x4*)&Ax[(r * 32 + ((c32 + 1) ^ (r & 7))) * 4];
            bf16x8 af;
            af[0] = (short)f2bf(a0.x); af[1] = (short)f2bf(a0.y);
            af[2] = (short)f2bf(a0.z); af[3] = (short)f2bf(a0.w);
            af[4] = (short)f2bf(a1.x); af[5] = (short)f2bf(a1.y);
            af[6] = (short)f2bf(a1.z); af[7] = (short)f2bf(a1.w);
            #pragma unroll
            for (int c = 0; c < 4; c++) {
                const int n = c * 16 + lrow;
                bf16x8 bf = *(const bf16x8*)&Wl[(n * 16 + ((kk * 4 + quad) ^ (n & 7))) * 8];
                acc[c] = __builtin_amdgcn_mfma_f32_16x16x32_bf16(af, bf, acc[c], 0, 0, 0);
            }
        }
    }

    const int orow = row0 + w * 16 + quad * 4;
    if (m < 2) {
        unsigned short* outp = (m == 0) ? qp : kp;
        const float sc = (m == 0) ? 0.125f : 1.0f;   // fold attn scale into qp
        #pragma unroll
        for (int c = 0; c < 4; c++)
            #pragma unroll
            for (int rr = 0; rr < 4; rr++)
                outp[(size_t)(orow + rr) * H_ + c * 16 + lrow] = f2bf(acc[c][rr]);
        if (m == 0) { // apply scale (separate loop keeps codegen simple)
            #pragma unroll
            for (int c = 0; c < 4; c++)
                #pragma unroll
                for (int rr = 0; rr < 4; rr++)
                    outp[(size_t)(orow + rr) * H_ + c * 16 + lrow] = f2bf(acc[c][rr] * sc);
        }
    } else {
        // vpT[b][h][s], s0..s0+3 contiguous per lane -> 8B stores
        const int bb = orow >> 11;
        const int s0 = orow & (S_ - 1);
        #pragma unroll
        for (int c = 0; c < 4; c++) {
            ushort4 u;
            u.x = f2bf(acc[c][0]); u.y = f2bf(acc[c][1]);
            u.z = f2bf(acc[c][2]); u.w = f2bf(acc[c][3]);
            *(ushort4*)&vpT[((size_t)bb * H_ + c * 16 + lrow) * S_ + s0] = u;
        }
    }
}

// Flash attention partial: block = (q-tile 64, batch, key-split). Max-free
// single-pass exp => partials over disjoint key ranges combine by addition.
// K and V^T tiles async-staged (L2-resident -> cheap barrier drain).
__global__ __launch_bounds__(256) void attn_kernel(
    const unsigned short* __restrict__ qp, const unsigned short* __restrict__ kp,
    const unsigned short* __restrict__ vpT, const float* __restrict__ mmul,
    float* __restrict__ po, float* __restrict__ pl)
{
    __shared__ unsigned short Qs[64][72];
    __shared__ unsigned short Ps[64][72];
    __shared__ unsigned short Ks[64 * 64];   // swizzled chunks [key][h]
    __shared__ unsigned short Vt[64 * 64];   // swizzled chunks [h][key]

    const int t = threadIdx.x;
    const int w = t >> 6, l = t & 63;
    const int lrow = l & 15, quad = l >> 4;
    const int b = blockIdx.y, q0 = blockIdx.x * 64, split = blockIdx.z;
    const int key0 = split * KPS;
    const size_t basebs = (size_t)b * S_;
    const unsigned short* vb = vpT + (size_t)b * H_ * S_;

    #pragma unroll
    for (int i = 0; i < 2; i++) {            // Q tile once: 512 16B-chunks
        int p = t + i * 256;
        int r = p >> 3, c8 = p & 7;
        u16x8 u = *(const u16x8*)&qp[(basebs + q0 + r) * H_ + c8 * 8];
        *(u16x8*)&Qs[r][c8 * 8] = u;
    }

    float lsum[4] = {0.f, 0.f, 0.f, 0.f};
    f32x4 o[4] = {};

    for (int kt = 0; kt < KPS / 64; kt++) {
        const int k0 = key0 + kt * 64;
        __syncthreads();                     // prev tile's LDS reads done
        #pragma unroll
        for (int j = 0; j < 2; j++) {        // K tile: 512 chunks
            int p = (w * 2 + j) * 64 + l;
            int r = p >> 3;
            int c8 = (p & 7) ^ (r & 7);
            async16(&kp[(basebs + k0 + r) * H_ + c8 * 8], &Ks[p * 8]);
        }
        #pragma unroll
        for (int j = 0; j < 2; j++) {        // V^T tile: 512 chunks
            int p = (w * 2 + j) * 64 + l;
            int h = p >> 3;
            int c8 = (p & 7) ^ (h & 7);
            async16(&vb[(size_t)h * S_ + k0 + c8 * 8], &Vt[p * 8]);
        }
        float mm[4];
        #pragma unroll
        for (int c = 0; c < 4; c++) mm[c] = mmul[basebs + k0 + c*16 + lrow];
        __syncthreads();                     // drain async queue

        // S = Q K^T (pre-scaled by 1/8 via qp)
        f32x4 s[4] = {};
        #pragma unroll
        for (int kk = 0; kk < 2; kk++) {
            bf16x8 aq = *(const bf16x8*)&Qs[w*16 + lrow][kk*32 + quad*8];
            #pragma unroll
            for (int c = 0; c < 4; c++) {
                const int n = c*16 + lrow;
                bf16x8 bk = *(const bf16x8*)&Ks[(n * 8 + ((kk*4 + quad) ^ (n & 7))) * 8];
                s[c] = __builtin_amdgcn_mfma_f32_16x16x32_bf16(aq, bk, s[c], 0, 0, 0);
            }
        }
        // single-pass softmax numerator; sum deferred
        #pragma unroll
        for (int r = 0; r < 4; r++) {
            float p0 = __expf(s[0][r]) * mm[0];
            float p1 = __expf(s[1][r]) * mm[1];
            float p2 = __expf(s[2][r]) * mm[2];
            float p3 = __expf(s[3][r]) * mm[3];
            lsum[r] += (p0 + p1) + (p2 + p3);
            const int pr = w*16 + quad*4 + r;
            Ps[pr][ 0 + lrow] = f2bf(p0);
            Ps[pr][16 + lrow] = f2bf(p1);
            Ps[pr][32 + lrow] = f2bf(p2);
            Ps[pr][48 + lrow] = f2bf(p3);
        }
        // Ps rows [w*16, w*16+16) wave-local: no barrier needed
        #pragma unroll
        for (int kk = 0; kk < 2; kk++) {
            bf16x8 ap = *(const bf16x8*)&Ps[w*16 + lrow][kk*32 + quad*8];
            #pragma unroll
            for (int c = 0; c < 4; c++) {
                const int h = c*16 + lrow;
                bf16x8 bv = *(const bf16x8*)&Vt[(h * 8 + ((kk*4 + quad) ^ (h & 7))) * 8];
                o[c] = __builtin_amdgcn_mfma_f32_16x16x32_bf16(ap, bv, o[c], 0, 0, 0);
            }
        }
    }

    float* pob = po + (size_t)split * M_ * H_;
    float* plb = pl + (size_t)split * M_;
    #pragma unroll
    for (int r = 0; r < 4; r++) {
        #pragma unroll
        for (int d = 1; d < 16; d <<= 1)
            lsum[r] += __shfl_xor(lsum[r], d, 64);
        const size_t row = basebs + q0 + w*16 + quad*4 + r;
        if (lrow == 0) plb[row] = lsum[r];
        #pragma unroll
        for (int c = 0; c < 4; c++)
            pob[row * H_ + c*16 + lrow] = o[c][r];
    }
}

// out = (sum_s po[s]) / (sum_s pl[s]); one float4 per thread.
__global__ __launch_bounds__(256) void combine_kernel(
    const float* __restrict__ po, const float* __restrict__ pl, float* __restrict__ out)
{
    const int idx = blockIdx.x * 256 + threadIdx.x;
    const size_t row = idx >> 4;
    const int c4 = (idx & 15) * 4;
    float lt = 0.f;
    #pragma unroll
    for (int s = 0; s < SPLIT; s++) lt += pl[(size_t)s * M_ + row];
    f32x4 acc = {};
    #pragma unroll
    for (int s = 0; s < SPLIT; s++) {
        const f32x4 p = *(const f32x4*)&po[((size_t)s * M_ + row) * H_ + c4];
        acc += p;
    }
    const float inv = 1.0f / lt;
    f32x4 r = acc * inv;
    *(f32x4*)&out[row * H_ + c4] = r;
}

extern "C" void kernel_launch(void* const* d_in, const int* in_sizes, int n_in,
                              void* d_out, int out_size, void* d_ws, size_t ws_size,
                              hipStream_t stream) {
    const float* q  = (const float*)d_in[0];
    const float* k  = (const float*)d_in[1];
    const float* v  = (const float*)d_in[2];
    const unsigned char* mask = (const unsigned char*)d_in[3];
    const float* Wq = (const float*)d_in[4];
    const float* Wk = (const float*)d_in[5];
    const float* Wv = (const float*)d_in[6];
    float* out = (float*)d_out;

    unsigned short* qp  = (unsigned short*)d_ws;         // 2 MB
    unsigned short* kp  = qp + (size_t)M_ * H_;          // 2 MB
    unsigned short* vpT = kp + (size_t)M_ * H_;          // 2 MB, [b][h][s]
    float* mmul = (float*)(vpT + (size_t)M_ * H_);       // 64 KB
    unsigned short* Wt = (unsigned short*)(mmul + M_);   // 384 KB
    float* po = (float*)(Wt + (size_t)3 * 64 * 1024);    // 16.8 MB
    float* pl = po + (size_t)SPLIT * M_ * H_;            // 256 KB

    wprep_kernel<<<dim3(16, 3), dim3(256), 0, stream>>>(Wq, Wk, Wv, Wt);
    mask_kernel<<<dim3((M_ + 255)/256), dim3(256), 0, stream>>>(mask, mmul, M_);
    proj_kernel<<<dim3(M_/64, 3), dim3(256), 0, stream>>>(q, k, v, Wt, qp, kp, vpT);
    attn_kernel<<<dim3(S_/64, B_, SPLIT), dim3(256), 0, stream>>>(qp, kp, vpT, mmul, po, pl);
    combine_kernel<<<dim3(M_*16/256), dim3(256), 0, stream>>>(po, pl, out);
}

// Round 6
// 243.195 us; speedup vs baseline: 1.0959x; 1.0045x over previous
//
#include <hip/hip_runtime.h>
#include <hip/hip_bf16.h>
#include <math.h>

#define B_ 8
#define S_ 2048
#define D_ 1024
#define H_ 64
#define M_ (B_*S_)
#define SPLIT 4
#define KPS (S_/SPLIT)   // 512 keys per split

typedef __attribute__((ext_vector_type(8))) short bf16x8;
typedef __attribute__((ext_vector_type(8))) unsigned short u16x8;
typedef __attribute__((ext_vector_type(4))) float f32x4;

__device__ inline unsigned short f2bf(float f) {
    unsigned int u = __builtin_bit_cast(unsigned int, f);
    u += 0x7fffu + ((u >> 16) & 1u);   // round-to-nearest-even
    return (unsigned short)(u >> 16);
}

// async global->LDS, 16B per lane (global side carries the bank swizzle).
__device__ inline void async16(const void* g, void* l) {
    __builtin_amdgcn_global_load_lds((const __attribute__((address_space(1))) void*)g,
                                     (__attribute__((address_space(3))) void*)l, 16, 0, 0);
}

// mask -> multiplicative 1.0/0.0. Layout sniff: jax bool may be 1-byte or int32.
__global__ __launch_bounds__(256) void mask_kernel(const unsigned char* __restrict__ mask,
                                                   float* __restrict__ mmul, int n) {
    int j = blockIdx.x * 256 + threadIdx.x;
    if (j >= n) return;
    bool boolLayout = mask[1] != 0;
    int mv = boolLayout ? (int)mask[j] : ((const int*)mask)[j];
    mmul[j] = mv ? 1.0f : 0.0f;
}

// Transpose W[1024][64] fp32 -> Wt[64][1024] bf16, one matrix per blockIdx.y.
__global__ __launch_bounds__(256) void wprep_kernel(
    const float* __restrict__ Wq, const float* __restrict__ Wk, const float* __restrict__ Wv,
    unsigned short* __restrict__ Wt)
{
    const int m = blockIdx.y;
    const float* W = (m == 0) ? Wq : (m == 1) ? Wk : Wv;
    unsigned short* Wo = Wt + (size_t)m * 64 * 1024;
    __shared__ unsigned short T[64][65];
    const int t = threadIdx.x;
    const int k0 = blockIdx.x * 64;
    #pragma unroll
    for (int i = 0; i < 16; i++) {
        int vi = t + i * 256;
        int kk = vi >> 6, n = vi & 63;
        T[kk][n] = f2bf(W[(size_t)(k0 + kk) * 64 + n]);
    }
    __syncthreads();
    #pragma unroll
    for (int i = 0; i < 4; i++) {
        int vi = t + i * 256;
        int n = vi >> 4, k4 = vi & 15;
        ushort4 u;
        u.x = T[k4*4+0][n]; u.y = T[k4*4+1][n]; u.z = T[k4*4+2][n]; u.w = T[k4*4+3][n];
        *(ushort4*)&Wo[(size_t)n * 1024 + k0 + k4*4] = u;
    }
}

// x[M,1024] @ W[1024,64]. Double-buffered async-LDS pipeline with RAW asm
// barriers + partial vmcnt: chunk k+1's loads stay in flight across the
// barrier (the AITER pattern __syncthreads cannot express -- it would force
// vmcnt(0)). Two bare barriers/iter; trailing one protects the buffer that
// gets re-filled next iteration. m==2 (v) writes TRANSPOSED vpT[b][h][s].
__global__ __launch_bounds__(256) void proj_kernel(
    const float* __restrict__ q, const float* __restrict__ kx, const float* __restrict__ vx,
    const unsigned short* __restrict__ Wt,
    unsigned short* __restrict__ qp, unsigned short* __restrict__ kp, unsigned short* __restrict__ vpT)
{
    __shared__ float          Ax[2][64 * 64];   // 16 KB each, chunk-swizzled
    __shared__ unsigned short Wl[2][64 * 64];   // 8 KB each, chunk-swizzled

    const int m = blockIdx.y;
    const float* x = (m == 0) ? q : (m == 1) ? kx : vx;
    const unsigned short* Wm = Wt + (size_t)m * 64 * 1024;

    const int t = threadIdx.x;
    const int w = t >> 6, l = t & 63;
    const int lrow = l & 15, quad = l >> 4;
    const int row0 = blockIdx.x * 64;

    f32x4 acc[4] = {};

    // issue one K=64 chunk (6 async insts per thread/wave)
    auto issue = [&](int ks, int bi) {
        #pragma unroll
        for (int j = 0; j < 4; j++) {            // A: 64r x 16 chunk-cols
            int p = j * 256 + t;
            int r = p >> 4;
            int cc = (p & 15) ^ (r & 7);
            async16(&x[(size_t)(row0 + r) * D_ + ks + cc * 4], &Ax[bi][p * 4]);
        }
        #pragma unroll
        for (int j = 0; j < 2; j++) {            // W: 64n x 8 chunk-cols
            int p = j * 256 + t;
            int n = p >> 3;
            int kc = (p & 7) ^ (n & 7);
            async16(&Wm[(size_t)n * 1024 + ks + kc * 8], &Wl[bi][p * 8]);
        }
    };

    auto compute = [&](int bi) {
        const int r = w * 16 + lrow;
        #pragma unroll
        for (int kk = 0; kk < 2; kk++) {
            const int c0 = kk * 8 + quad * 2;
            f32x4 a0 = *(const f32x4*)&Ax[bi][(r * 16 + ((c0    ) ^ (r & 7))) * 4];
            f32x4 a1 = *(const f32x4*)&Ax[bi][(r * 16 + ((c0 + 1) ^ (r & 7))) * 4];
            bf16x8 af;
            af[0] = (short)f2bf(a0.x); af[1] = (short)f2bf(a0.y);
            af[2] = (short)f2bf(a0.z); af[3] = (short)f2bf(a0.w);
            af[4] = (short)f2bf(a1.x); af[5] = (short)f2bf(a1.y);
            af[6] = (short)f2bf(a1.z); af[7] = (short)f2bf(a1.w);
            #pragma unroll
            for (int c = 0; c < 4; c++) {
                const int n = c * 16 + lrow;
                bf16x8 bf = *(const bf16x8*)&Wl[bi][(n * 8 + ((kk * 4 + quad) ^ (n & 7))) * 8];
                acc[c] = __builtin_amdgcn_mfma_f32_16x16x32_bf16(af, bf, acc[c], 0, 0, 0);
            }
        }
    };

    issue(0, 0);
    #pragma unroll 1
    for (int kc = 0; kc < 15; kc++) {
        issue((kc + 1) * 64, (kc + 1) & 1);
        // wait only chunk kc's 6 loads (newest 6 remain in flight), then sync
        asm volatile("s_waitcnt vmcnt(6)\n\ts_barrier" ::: "memory");
        compute(kc & 1);
        // all waves done reading buf kc&1 before it is re-filled next iter
        asm volatile("s_barrier" ::: "memory");
    }
    asm volatile("s_waitcnt vmcnt(0)\n\ts_barrier" ::: "memory");
    compute(1);

    const int orow = row0 + w * 16 + quad * 4;
    if (m < 2) {
        unsigned short* outp = (m == 0) ? qp : kp;
        const float sc = (m == 0) ? 0.125f : 1.0f;   // fold attn scale into qp
        #pragma unroll
        for (int c = 0; c < 4; c++)
            #pragma unroll
            for (int rr = 0; rr < 4; rr++)
                outp[(size_t)(orow + rr) * H_ + c * 16 + lrow] = f2bf(acc[c][rr] * sc);
    } else {
        // vpT[b][h][s], s0..s0+3 contiguous per lane -> 8B stores
        const int bb = orow >> 11;
        const int s0 = orow & (S_ - 1);
        #pragma unroll
        for (int c = 0; c < 4; c++) {
            ushort4 u;
            u.x = f2bf(acc[c][0]); u.y = f2bf(acc[c][1]);
            u.z = f2bf(acc[c][2]); u.w = f2bf(acc[c][3]);
            *(ushort4*)&vpT[((size_t)bb * H_ + c * 16 + lrow) * S_ + s0] = u;
        }
    }
}

// Flash attention partial: block = (q-tile 64, batch, key-split). Max-free
// single-pass exp => partials over disjoint key ranges combine by addition.
// K and V^T tiles async-staged (L2-resident -> cheap barrier drain).
__global__ __launch_bounds__(256) void attn_kernel(
    const unsigned short* __restrict__ qp, const unsigned short* __restrict__ kp,
    const unsigned short* __restrict__ vpT, const float* __restrict__ mmul,
    float* __restrict__ po, float* __restrict__ pl)
{
    __shared__ unsigned short Qs[64][72];
    __shared__ unsigned short Ps[64][72];
    __shared__ unsigned short Ks[64 * 64];   // swizzled chunks [key][h]
    __shared__ unsigned short Vt[64 * 64];   // swizzled chunks [h][key]

    const int t = threadIdx.x;
    const int w = t >> 6, l = t & 63;
    const int lrow = l & 15, quad = l >> 4;
    const int b = blockIdx.y, q0 = blockIdx.x * 64, split = blockIdx.z;
    const int key0 = split * KPS;
    const size_t basebs = (size_t)b * S_;
    const unsigned short* vb = vpT + (size_t)b * H_ * S_;

    #pragma unroll
    for (int i = 0; i < 2; i++) {            // Q tile once: 512 16B-chunks
        int p = t + i * 256;
        int r = p >> 3, c8 = p & 7;
        u16x8 u = *(const u16x8*)&qp[(basebs + q0 + r) * H_ + c8 * 8];
        *(u16x8*)&Qs[r][c8 * 8] = u;
    }

    float lsum[4] = {0.f, 0.f, 0.f, 0.f};
    f32x4 o[4] = {};

    for (int kt = 0; kt < KPS / 64; kt++) {
        const int k0 = key0 + kt * 64;
        __syncthreads();                     // prev tile's LDS reads done
        #pragma unroll
        for (int j = 0; j < 2; j++) {        // K tile: 512 chunks
            int p = (w * 2 + j) * 64 + l;
            int r = p >> 3;
            int c8 = (p & 7) ^ (r & 7);
            async16(&kp[(basebs + k0 + r) * H_ + c8 * 8], &Ks[p * 8]);
        }
        #pragma unroll
        for (int j = 0; j < 2; j++) {        // V^T tile: 512 chunks
            int p = (w * 2 + j) * 64 + l;
            int h = p >> 3;
            int c8 = (p & 7) ^ (h & 7);
            async16(&vb[(size_t)h * S_ + k0 + c8 * 8], &Vt[p * 8]);
        }
        float mm[4];
        #pragma unroll
        for (int c = 0; c < 4; c++) mm[c] = mmul[basebs + k0 + c*16 + lrow];
        __syncthreads();                     // drain async queue

        // S = Q K^T (pre-scaled by 1/8 via qp)
        f32x4 s[4] = {};
        #pragma unroll
        for (int kk = 0; kk < 2; kk++) {
            bf16x8 aq = *(const bf16x8*)&Qs[w*16 + lrow][kk*32 + quad*8];
            #pragma unroll
            for (int c = 0; c < 4; c++) {
                const int n = c*16 + lrow;
                bf16x8 bk = *(const bf16x8*)&Ks[(n * 8 + ((kk*4 + quad) ^ (n & 7))) * 8];
                s[c] = __builtin_amdgcn_mfma_f32_16x16x32_bf16(aq, bk, s[c], 0, 0, 0);
            }
        }
        // single-pass softmax numerator; sum deferred
        #pragma unroll
        for (int r = 0; r < 4; r++) {
            float p0 = __expf(s[0][r]) * mm[0];
            float p1 = __expf(s[1][r]) * mm[1];
            float p2 = __expf(s[2][r]) * mm[2];
            float p3 = __expf(s[3][r]) * mm[3];
            lsum[r] += (p0 + p1) + (p2 + p3);
            const int pr = w*16 + quad*4 + r;
            Ps[pr][ 0 + lrow] = f2bf(p0);
            Ps[pr][16 + lrow] = f2bf(p1);
            Ps[pr][32 + lrow] = f2bf(p2);
            Ps[pr][48 + lrow] = f2bf(p3);
        }
        // Ps rows [w*16, w*16+16) wave-local: no barrier needed
        #pragma unroll
        for (int kk = 0; kk < 2; kk++) {
            bf16x8 ap = *(const bf16x8*)&Ps[w*16 + lrow][kk*32 + quad*8];
            #pragma unroll
            for (int c = 0; c < 4; c++) {
                const int h = c*16 + lrow;
                bf16x8 bv = *(const bf16x8*)&Vt[(h * 8 + ((kk*4 + quad) ^ (h & 7))) * 8];
                o[c] = __builtin_amdgcn_mfma_f32_16x16x32_bf16(ap, bv, o[c], 0, 0, 0);
            }
        }
    }

    float* pob = po + (size_t)split * M_ * H_;
    float* plb = pl + (size_t)split * M_;
    #pragma unroll
    for (int r = 0; r < 4; r++) {
        #pragma unroll
        for (int d = 1; d < 16; d <<= 1)
            lsum[r] += __shfl_xor(lsum[r], d, 64);
        const size_t row = basebs + q0 + w*16 + quad*4 + r;
        if (lrow == 0) plb[row] = lsum[r];
        #pragma unroll
        for (int c = 0; c < 4; c++)
            pob[row * H_ + c*16 + lrow] = o[c][r];
    }
}

// out = (sum_s po[s]) / (sum_s pl[s]); one float4 per thread.
__global__ __launch_bounds__(256) void combine_kernel(
    const float* __restrict__ po, const float* __restrict__ pl, float* __restrict__ out)
{
    const int idx = blockIdx.x * 256 + threadIdx.x;
    const size_t row = idx >> 4;
    const int c4 = (idx & 15) * 4;
    float lt = 0.f;
    #pragma unroll
    for (int s = 0; s < SPLIT; s++) lt += pl[(size_t)s * M_ + row];
    f32x4 acc = {};
    #pragma unroll
    for (int s = 0; s < SPLIT; s++) {
        const f32x4 p = *(const f32x4*)&po[((size_t)s * M_ + row) * H_ + c4];
        acc += p;
    }
    const float inv = 1.0f / lt;
    f32x4 r = acc * inv;
    *(f32x4*)&out[row * H_ + c4] = r;
}

extern "C" void kernel_launch(void* const* d_in, const int* in_sizes, int n_in,
                              void* d_out, int out_size, void* d_ws, size_t ws_size,
                              hipStream_t stream) {
    const float* q  = (const float*)d_in[0];
    const float* k  = (const float*)d_in[1];
    const float* v  = (const float*)d_in[2];
    const unsigned char* mask = (const unsigned char*)d_in[3];
    const float* Wq = (const float*)d_in[4];
    const float* Wk = (const float*)d_in[5];
    const float* Wv = (const float*)d_in[6];
    float* out = (float*)d_out;

    unsigned short* qp  = (unsigned short*)d_ws;         // 2 MB
    unsigned short* kp  = qp + (size_t)M_ * H_;          // 2 MB
    unsigned short* vpT = kp + (size_t)M_ * H_;          // 2 MB, [b][h][s]
    float* mmul = (float*)(vpT + (size_t)M_ * H_);       // 64 KB
    unsigned short* Wt = (unsigned short*)(mmul + M_);   // 384 KB
    float* po = (float*)(Wt + (size_t)3 * 64 * 1024);    // 16.8 MB
    float* pl = po + (size_t)SPLIT * M_ * H_;            // 256 KB

    wprep_kernel<<<dim3(16, 3), dim3(256), 0, stream>>>(Wq, Wk, Wv, Wt);
    mask_kernel<<<dim3((M_ + 255)/256), dim3(256), 0, stream>>>(mask, mmul, M_);
    proj_kernel<<<dim3(M_/64, 3), dim3(256), 0, stream>>>(q, k, v, Wt, qp, kp, vpT);
    attn_kernel<<<dim3(S_/64, B_, SPLIT), dim3(256), 0, stream>>>(qp, kp, vpT, mmul, po, pl);
    combine_kernel<<<dim3(M_*16/256), dim3(256), 0, stream>>>(po, pl, out);
}